// Round 16
// baseline (474.784 us; speedup 1.0000x reference)
//
#include <hip/hip_runtime.h>

typedef unsigned short u16;
typedef __bf16 bf16x8 __attribute__((ext_vector_type(8)));
typedef float f32x4 __attribute__((ext_vector_type(4)));
typedef float f32x16 __attribute__((ext_vector_type(16)));

__device__ __forceinline__ u16 f2bf(float f) {
    unsigned u = __float_as_uint(f);
    u = (u + 0x7FFFu + ((u >> 16) & 1u)) >> 16;
    return (u16)u;
}
__device__ __forceinline__ float bf2f(u16 h) {
    return __uint_as_float(((unsigned)h) << 16);
}

// async global -> LDS, 16B per lane
__device__ __forceinline__ void gld16(const u16* g, u16* l) {
    __builtin_amdgcn_global_load_lds((const __attribute__((address_space(1))) void*)g,
                                     (__attribute__((address_space(3))) void*)l, 16, 0, 0);
}

// st_16x32 subtiled swizzle for a [R][64] bf16 tile staged as 16x32 subtiles.
__device__ __forceinline__ int swz(int row, int col) {
    return ((row >> 4) * 2 + (col >> 5)) * 512 + (row & 15) * 32 +
           ((col & 31) ^ ((row & 8) ? 16 : 0));
}

// ---------------- convert fp32 -> bf16 (flat) ----------------
__global__ __launch_bounds__(256) void cvt_kernel(const float* __restrict__ in,
                                                  u16* __restrict__ out, long n) {
    long i = ((long)blockIdx.x * blockDim.x + threadIdx.x) * 4;
    if (i + 3 < n) {
        float4 v = *(const float4*)&in[i];
        __align__(8) u16 r[4] = {f2bf(v.x), f2bf(v.y), f2bf(v.z), f2bf(v.w)};
        *(int2*)&out[i] = *(const int2*)r;
    }
}

// ---------------- transpose (+convert) -> bf16 ----------------
template <int INF32>
__global__ __launch_bounds__(256) void transpose_to_bf16(const void* __restrict__ in,
                                                         u16* __restrict__ out, int R, int C,
                                                         long inB, long outB) {
    __shared__ float tile[32][33];
    const long zi = (long)blockIdx.z * inB;
    const long zo = (long)blockIdx.z * outB;
    const int c0 = blockIdx.x * 32, r0 = blockIdx.y * 32;
    const int tx = threadIdx.x & 31;
    const int ty = threadIdx.x >> 5;  // 0..7
#pragma unroll
    for (int i = 0; i < 32; i += 8) {
        long idx = zi + (long)(r0 + ty + i) * C + c0 + tx;
        float v = INF32 ? ((const float*)in)[idx] : bf2f(((const u16*)in)[idx]);
        tile[ty + i][tx] = v;
    }
    __syncthreads();
#pragma unroll
    for (int i = 0; i < 32; i += 8) {
        out[zo + (long)(c0 + ty + i) * R + r0 + tx] = f2bf(tile[tx][ty + i]);
    }
}

// ---------------- 256x256 NT bf16 MFMA GEMM (32x32x16), counted-vmcnt pipeline ----
// C[M,N] = act(scale * (A[M,K] @ B[N,K]^T) + bias) [* rscale(row)]
// act: 0=none 1=relu 2=exp(x-32)
// 8 waves (2Mx4N), BK=64, 128KB double-buffered LDS, st_16x32 swizzle.
// R12 schedule verbatim; MFMA shape switched 16x16x32 -> 32x32x16 (2495 vs
// 2176 TF ubench; half the MFMA issues/FLOP -> frees issue slots for
// ds_read/staging co-issue). Per wave: 4 m-tiles x 2 n-tiles of 32x32;
// A/B frag: row=lane&31, k=(lane>>5)*8..+7; C/D: col=lane&31,
// row=(reg&3)+8*(reg>>2)+4*(lane>>5)  [HW-verified m74/m101].
// Non-symm: column-major block order within each XCD chunk. symm: balanced
// triangle (batch==XCD); mirror tile assembled in LDS, coalesced write-back.
template <int OUTBF>
__global__ __launch_bounds__(512, 2) void gemm_nt(const u16* __restrict__ A,
                                                  const u16* __restrict__ Bm,
                                                  void* __restrict__ Cout, int M, int N, int K,
                                                  long sA, long sB, long sC,
                                                  const float* __restrict__ bias, int act,
                                                  float scale, int symm,
                                                  const float* __restrict__ rscale) {
    int bx, by, zz;
    if (symm) {
        const int q = gridDim.x >> 3;
        const int orig = blockIdx.x;
        const int wgid = (orig & 7) * q + (orig >> 3);
        const int NB = N >> 8;
        const int nTri = (NB * (NB + 1)) >> 1;
        zz = wgid / nTri;
        int t = wgid - zz * nTri;
        by = 0;
        int rem = NB;
        while (t >= rem) {
            t -= rem;
            --rem;
            ++by;
        }
        bx = by + t;
    } else {
        const int nx = gridDim.x;
        const int nwg = nx * gridDim.y;
        const int orig = blockIdx.y * nx + blockIdx.x;
        const int q = nwg >> 3, r = nwg & 7, xcd = orig & 7, o8 = orig >> 3;
        const int wgid = (xcd < r ? xcd * (q + 1) : r * (q + 1) + (xcd - r) * q) + o8;
        if (r == 0 && (q % nx) == 0) {
            const int rpc = q / nx;  // block-rows per XCD chunk
            const int o = wgid - xcd * q;
            by = xcd * rpc + (o % rpc);
            bx = o / rpc;
        } else {
            bx = wgid % nx;
            by = wgid / nx;
        }
        zz = blockIdx.z;
    }

    // SM: As(32768 shorts) + Bs(32768); mirror tile T (256x264) overlays all.
    __shared__ __align__(16) u16 SM[67584];
    u16(*As)[256 * 64] = (u16(*)[256 * 64])SM;
    u16(*Bs)[256 * 64] = (u16(*)[256 * 64])(SM + 32768);
    u16* T = SM;
    const int tid = threadIdx.x;  // 0..511
    const int lane = tid & 63;
    const int wid = tid >> 6;  // 0..7
    const int wr = wid >> 2;   // 0..1
    const int wc = wid & 3;    // 0..3
    const int l31 = lane & 31, lh = lane >> 5;
    const long zA = (long)zz * sA;
    const long zB = (long)zz * sB;
    const long zC = (long)zz * sC;
    const int m0 = by * 256, n0 = bx * 256;
    const u16* Ab = A + zA + (long)m0 * K;
    const u16* Bb = Bm + zB + (long)n0 * K;
    const int nt = K >> 6;

    f32x16 acc[4][2] = {};

    // one chunk = 2 gld16/thread (1KB/wave into A + 1KB into B); 4 chunks/tile.
    auto stage_chunk = [&](int t, int b, int j) {
        const int c = j * 512 + tid;
        const int s = c >> 6, r = (c >> 2) & 15;
        const int row = (s >> 1) * 16 + r;
        const int col = (s & 1) * 32 + (((c & 3) * 8) ^ ((r & 8) ? 16 : 0));
        gld16(Ab + (long)row * K + t * 64 + col, &As[b][c * 8]);
        gld16(Bb + (long)row * K + t * 64 + col, &Bs[b][c * 8]);
    };

#pragma unroll
    for (int j = 0; j < 4; ++j) stage_chunk(0, 0, j);
    if (nt > 1) {
        stage_chunk(1, 1, 0);
        asm volatile("s_waitcnt vmcnt(2)" ::: "memory");
    } else {
        asm volatile("s_waitcnt vmcnt(0)" ::: "memory");
    }
    __builtin_amdgcn_s_barrier();

    for (int t = 0; t < nt; ++t) {
        const int cur = t & 1;
        bf16x8 bf[2][4];
#pragma unroll
        for (int n2 = 0; n2 < 2; ++n2)
#pragma unroll
            for (int ks = 0; ks < 4; ++ks)
                bf[n2][ks] =
                    *(const bf16x8*)&Bs[cur][swz(wc * 64 + n2 * 32 + l31, ks * 16 + lh * 8)];
        bf16x8 af[2][4];
#pragma unroll
        for (int ks = 0; ks < 4; ++ks)
            af[0][ks] = *(const bf16x8*)&As[cur][swz(wr * 128 + l31, ks * 16 + lh * 8)];
#pragma unroll
        for (int mt = 0; mt < 4; ++mt) {
            if (mt < 3) {
#pragma unroll
                for (int ks = 0; ks < 4; ++ks)
                    af[(mt + 1) & 1][ks] = *(const bf16x8*)&As[cur][swz(
                        wr * 128 + (mt + 1) * 32 + l31, ks * 16 + lh * 8)];
                if (t + 1 < nt) stage_chunk(t + 1, cur ^ 1, mt + 1);
            }
            __builtin_amdgcn_s_setprio(1);
#pragma unroll
            for (int n2 = 0; n2 < 2; ++n2)
#pragma unroll
                for (int ks = 0; ks < 4; ++ks)
                    acc[mt][n2] = __builtin_amdgcn_mfma_f32_32x32x16_bf16(
                        af[mt & 1][ks], bf[n2][ks], acc[mt][n2], 0, 0, 0);
            __builtin_amdgcn_s_setprio(0);
        }
        // transition: free buf cur, prefetch chunk0 of tile t+2 into it, publish cur^1
        __builtin_amdgcn_s_barrier();
        if (t + 2 < nt) {
            stage_chunk(t + 2, cur, 0);
            asm volatile("s_waitcnt vmcnt(2)" ::: "memory");
        } else {
            asm volatile("s_waitcnt vmcnt(0)" ::: "memory");
        }
        __builtin_amdgcn_s_barrier();
    }

    const int mirror = symm && (bx > by);
#pragma unroll
    for (int n2 = 0; n2 < 2; ++n2) {
        const int col = n0 + wc * 64 + n2 * 32 + l31;
        const float bv = bias ? bias[col] : 0.0f;
#pragma unroll
        for (int mt = 0; mt < 4; ++mt) {
#pragma unroll
            for (int q = 0; q < 4; ++q) {
                const int rowb = m0 + wr * 128 + mt * 32 + q * 8 + lh * 4;
                float v[4];
#pragma unroll
                for (int r = 0; r < 4; ++r) {
                    float f = acc[mt][n2][q * 4 + r] * scale + bv;
                    if (act == 1)
                        f = fmaxf(f, 0.0f);
                    else if (act == 2)
                        f = __expf(f - 32.0f);
                    if (rscale) f *= rscale[(long)zz * M + rowb + r];
                    v[r] = f;
                    if (OUTBF)
                        ((u16*)Cout)[zC + (long)(rowb + r) * N + col] = f2bf(f);
                    else
                        ((float*)Cout)[zC + (long)(rowb + r) * N + col] = f;
                }
                if (mirror) {
                    if (OUTBF) {
                        // stage transposed element block into LDS tile T[col][row]
                        const int cl = wc * 64 + n2 * 32 + l31;
                        const int rl = wr * 128 + mt * 32 + q * 8 + lh * 4;
                        __align__(8) u16 tv[4] = {f2bf(v[0]), f2bf(v[1]), f2bf(v[2]),
                                                  f2bf(v[3])};
                        *(int2*)&T[cl * 264 + rl] = *(const int2*)tv;
                    } else {
                        *(float4*)&((float*)Cout)[zC + (long)col * N + rowb] =
                            make_float4(v[0], v[1], v[2], v[3]);
                    }
                }
            }
        }
    }
    if (mirror && OUTBF) {
        __builtin_amdgcn_s_barrier();
#pragma unroll
        for (int i = 0; i < 16; ++i) {
            const int c = i * 512 + tid;  // 8192 16B-chunks: 256 rows x 32
            const int tr = c >> 5, tc = c & 31;
            *(int4*)&((u16*)Cout)[zC + (long)(n0 + tr) * N + m0 + tc * 8] =
                *(const int4*)&T[tr * 264 + tc * 8];
        }
    }
}

// ---------------- LayerNorm, wave-per-row (bf16 in/out, in-place) ----------------
template <int CH>
__global__ __launch_bounds__(256) void ln_wave(u16* __restrict__ x, const float* __restrict__ g,
                                               const float* __restrict__ be) {
    const int lane = threadIdx.x & 63;
    const int wid = threadIdx.x >> 6;
    const long row = (long)blockIdx.x * 4 + wid;
    u16* p = x + row * (CH * 512);
    __align__(16) u16 raw[CH][8];
    float s = 0.f, ss = 0.f;
#pragma unroll
    for (int c = 0; c < CH; ++c) {
        *(int4*)raw[c] = *(const int4*)&p[(c * 64 + lane) * 8];
#pragma unroll
        for (int j = 0; j < 8; ++j) {
            float f = bf2f(raw[c][j]);
            s += f;
            ss += f * f;
        }
    }
#pragma unroll
    for (int o = 1; o < 64; o <<= 1) {
        s += __shfl_xor(s, o);
        ss += __shfl_xor(ss, o);
    }
    const float inv = 1.0f / (float)(CH * 512);
    const float mu = s * inv;
    const float var = ss * inv - mu * mu;
    const float rs = rsqrtf(var + 1e-5f);
#pragma unroll
    for (int c = 0; c < CH; ++c) {
        const int base = (c * 64 + lane) * 8;
        float4 g0 = *(const float4*)&g[base];
        float4 g1 = *(const float4*)&g[base + 4];
        float4 b0 = *(const float4*)&be[base];
        float4 b1 = *(const float4*)&be[base + 4];
        float gv[8] = {g0.x, g0.y, g0.z, g0.w, g1.x, g1.y, g1.z, g1.w};
        float bv[8] = {b0.x, b0.y, b0.z, b0.w, b1.x, b1.y, b1.z, b1.w};
#pragma unroll
        for (int j = 0; j < 8; ++j)
            raw[c][j] = f2bf((bf2f(raw[c][j]) - mu) * rs * gv[j] + bv[j]);
        *(int4*)&p[base] = *(const int4*)raw[c];
    }
}

// ---------------- normalize: weights = E/rowsum -> d_out fp32, rowInv ----------------
__global__ __launch_bounds__(256) void norm_wave(const u16* __restrict__ e,
                                                 float* __restrict__ outw,
                                                 float* __restrict__ rowInv) {
    const int lane = threadIdx.x & 63;
    const int wid = threadIdx.x >> 6;
    const long row = (long)blockIdx.x * 4 + wid;
    const u16* p = e + row * 2048;
    float v[4][8];
    float s = 0.f;
#pragma unroll
    for (int c = 0; c < 4; ++c) {
        __align__(16) u16 raw[8];
        *(int4*)raw = *(const int4*)&p[(c * 64 + lane) * 8];
#pragma unroll
        for (int j = 0; j < 8; ++j) {
            v[c][j] = bf2f(raw[j]);
            s += v[c][j];
        }
    }
#pragma unroll
    for (int o = 1; o < 64; o <<= 1) s += __shfl_xor(s, o);
    const float inv = 1.0f / s;
    if (lane == 0) rowInv[row] = inv;
    float* q = outw + row * 2048;
#pragma unroll
    for (int c = 0; c < 4; ++c) {
        const int base = (c * 64 + lane) * 8;
        float4 o0 = make_float4(v[c][0] * inv, v[c][1] * inv, v[c][2] * inv, v[c][3] * inv);
        float4 o1 = make_float4(v[c][4] * inv, v[c][5] * inv, v[c][6] * inv, v[c][7] * inv);
        *(float4*)&q[base] = o0;
        *(float4*)&q[base + 4] = o1;
    }
}

// ---------------- head: attended(bf16) @ WhT + bh -> gates -> log ----------------
__global__ __launch_bounds__(256) void head_kernel(const u16* __restrict__ A,
                                                   const u16* __restrict__ WhT,
                                                   const float* __restrict__ bh,
                                                   const float* __restrict__ prior,
                                                   const float* __restrict__ ag,
                                                   const float* __restrict__ og,
                                                   float* __restrict__ out) {
    __shared__ __align__(16) u16 As2[128 * 64];
    __shared__ __align__(16) u16 Bs2[64 * 64];
    const int tid = threadIdx.x;
    const int lane = tid & 63;
    const int wid = tid >> 6;
    const int l15 = lane & 15, lg = lane >> 4;
    const int m0 = blockIdx.x * 128;
    const int srow = tid >> 3, scol = (tid & 7) * 8;
    const u16* pa = A + (long)(m0 + srow) * 1024 + scol;
    const u16* pb = WhT + (long)srow * 1024 + scol;

    f32x4 acc[2][4] = {};
    for (int k0 = 0; k0 < 1024; k0 += 64) {
#pragma unroll
        for (int i = 0; i < 4; ++i) gld16(pa + (long)i * 32 * 1024 + k0, &As2[i * 2048 + tid * 8]);
#pragma unroll
        for (int i = 0; i < 2; ++i) gld16(pb + (long)i * 32 * 1024 + k0, &Bs2[i * 2048 + tid * 8]);
        __syncthreads();
#pragma unroll
        for (int kk = 0; kk < 2; ++kk) {
            bf16x8 af[2], bfr[4];
#pragma unroll
            for (int m = 0; m < 2; ++m)
                af[m] = *(const bf16x8*)&As2[(wid * 32 + m * 16 + l15) * 64 + kk * 32 + lg * 8];
#pragma unroll
            for (int n = 0; n < 4; ++n)
                bfr[n] = *(const bf16x8*)&Bs2[(n * 16 + l15) * 64 + kk * 32 + lg * 8];
#pragma unroll
            for (int m = 0; m < 2; ++m)
#pragma unroll
                for (int n = 0; n < 4; ++n)
                    acc[m][n] =
                        __builtin_amdgcn_mfma_f32_16x16x32_bf16(af[m], bfr[n], acc[m][n], 0, 0, 0);
        }
        __syncthreads();
    }

#pragma unroll
    for (int n = 0; n < 4; ++n) {
        const int col = n * 16 + l15;
        const float bhv = bh[col];
        const float agv = ag[col];
        const float ogv = og[col];
#pragma unroll
        for (int m = 0; m < 2; ++m) {
#pragma unroll
            for (int r = 0; r < 4; ++r) {
                const int row = m0 + wid * 32 + m * 16 + lg * 4 + r;
                const float logit = acc[m][n][r] + bhv;
                const int b = row >> 11;
                const float sp = 1.f / (1.f + expf(-prior[b * 64 + col]));
                const float sl = 1.f / (1.f + expf(-logit));
                const float av = fminf(sl, sp) * agv;
                const float ov = fmaxf(sl, sp) * ogv;
                out[(long)row * 64 + col] = logf((av + ov) * 0.5f + 1e-10f);
            }
        }
    }
}

extern "C" void kernel_launch(void* const* d_in, const int* in_sizes, int n_in, void* d_out,
                              int out_size, void* d_ws, size_t ws_size, hipStream_t stream) {
    const float* emb = (const float*)d_in[0];
    const float* prior = (const float*)d_in[1];
    const float* W1 = (const float*)d_in[2];
    const float* b1 = (const float*)d_in[3];
    const float* g1 = (const float*)d_in[4];
    const float* be1 = (const float*)d_in[5];
    const float* W2 = (const float*)d_in[6];
    const float* b2 = (const float*)d_in[7];
    const float* g2 = (const float*)d_in[8];
    const float* be2 = (const float*)d_in[9];
    const float* Wh = (const float*)d_in[10];
    const float* bh = (const float*)d_in[11];
    const float* ag = (const float*)d_in[12];
    const float* og = (const float*)d_in[13];

    const int Bn = 8, S = 2048, DIN = 1024, H1 = 2048, H2 = 1024, Cc = 64;
    const int M = Bn * S;  // 16384

    char* ws = (char*)d_ws;
    size_t off = 0;
    auto alloc = [&](size_t b) {
        size_t o = off;
        off += (b + 255) & ~(size_t)255;
        return o;
    };
    // Live-range-shared regions (peak ~136.2 MB, under the proven 277 MB):
    //   R0 (64MB): h (steps 4-6)      then attnb/E (steps 9-11)
    //   R1 (32MB): embb (steps 1-4)   then featT (steps 8-11)
    //   R2 (32MB): feat (steps 6-9)   then attd (steps 11-12)
    char* R0 = ws + alloc((size_t)M * H1 * 2);
    char* R1 = ws + alloc((size_t)M * DIN * 2);
    char* R2 = ws + alloc((size_t)M * H2 * 2);
    u16* W1t = (u16*)(ws + alloc((size_t)H1 * DIN * 2));
    u16* W2t = (u16*)(ws + alloc((size_t)H2 * H1 * 2));
    u16* WhT = (u16*)(ws + alloc((size_t)Cc * H2 * 2));
    float* rowInv = (float*)(ws + alloc((size_t)M * 4));

    u16* h = (u16*)R0;
    u16* attnb = (u16*)R0;
    u16* embb = (u16*)R1;
    u16* featT = (u16*)R1;
    u16* feat = (u16*)R2;
    u16* attd = (u16*)R2;

    float* out_logits = (float*)d_out;
    float* out_attn = out_logits + (size_t)M * Cc;

    // 1. embeddings -> bf16
    cvt_kernel<<<(int)(((long)M * DIN) / 1024), 256, 0, stream>>>(emb, embb, (long)M * DIN);
    // 2. W1 [DIN][H1] -> W1t [H1][DIN]
    transpose_to_bf16<1><<<dim3(H1 / 32, DIN / 32, 1), 256, 0, stream>>>(W1, W1t, DIN, H1, 0, 0);
    // 3. W2 [H1][H2] -> W2t [H2][H1]
    transpose_to_bf16<1><<<dim3(H2 / 32, H1 / 32, 1), 256, 0, stream>>>(W2, W2t, H1, H2, 0, 0);
    // 3b. Wh [H2][C] -> WhT [C][H2]
    transpose_to_bf16<1><<<dim3(Cc / 32, H2 / 32, 1), 256, 0, stream>>>(Wh, WhT, H2, Cc, 0, 0);
    // 4. h = relu(emb @ W1 + b1)   [M,H1] bf16
    gemm_nt<1><<<dim3(H1 / 256, M / 256, 1), 512, 0, stream>>>(embb, W1t, h, M, H1, DIN, 0, 0, 0,
                                                               b1, 1, 1.0f, 0, nullptr);
    // 5. LN1 (wave-per-row)
    ln_wave<4><<<M / 4, 256, 0, stream>>>(h, g1, be1);
    // 6. feat = relu(h @ W2 + b2)  [M,H2] bf16
    gemm_nt<1><<<dim3(H2 / 256, M / 256, 1), 512, 0, stream>>>(h, W2t, feat, M, H2, H1, 0, 0, 0,
                                                               b2, 1, 1.0f, 0, nullptr);
    // 7. LN2
    ln_wave<2><<<M / 4, 256, 0, stream>>>(feat, g2, be2);
    // 8. featT per batch: [S][H2] -> [H2][S]
    transpose_to_bf16<0><<<dim3(H2 / 32, S / 32, Bn), 256, 0, stream>>>(
        feat, featT, S, H2, (long)S * H2, (long)H2 * S);
    // 9. E = exp(feat@feat^T/32 - 32) bf16 -> attnb, balanced triangle + LDS mirror
    {
        const int NB = S / 256;              // 8
        const int nTri = NB * (NB + 1) / 2;  // 36
        gemm_nt<1><<<dim3(nTri * Bn, 1, 1), 512, 0, stream>>>(
            feat, feat, attnb, S, S, H2, (long)S * H2, (long)S * H2, (long)S * S, nullptr,
            /*act=*/2, 0.03125f, /*symm=*/1, nullptr);
    }
    // 10. normalize: attention weights fp32 -> d_out, rowInv for attended
    norm_wave<<<M / 4, 256, 0, stream>>>(attnb, out_attn, rowInv);
    // 11. attended = (E @ featT) * rowInv   [S,H2] bf16 per batch
    gemm_nt<1><<<dim3(H2 / 256, S / 256, Bn), 512, 0, stream>>>(attnb, featT, attd, S, H2, S,
                                                                (long)S * S, (long)H2 * S,
                                                                (long)S * H2, nullptr, 0, 1.0f, 0,
                                                                rowInv);
    // 12. head + logic gates + log (MFMA)
    head_kernel<<<M / 128, 256, 0, stream>>>(attd, WhT, bh, prior, ag, og, out_logits);
}

// Round 17
// 453.387 us; speedup vs baseline: 1.0472x; 1.0472x over previous
//
#include <hip/hip_runtime.h>

typedef unsigned short u16;
typedef __bf16 bf16x8 __attribute__((ext_vector_type(8)));
typedef float f32x4 __attribute__((ext_vector_type(4)));

__device__ __forceinline__ u16 f2bf(float f) {
    unsigned u = __float_as_uint(f);
    u = (u + 0x7FFFu + ((u >> 16) & 1u)) >> 16;
    return (u16)u;
}
__device__ __forceinline__ float bf2f(u16 h) {
    return __uint_as_float(((unsigned)h) << 16);
}

// async global -> LDS, 16B per lane
__device__ __forceinline__ void gld16(const u16* g, u16* l) {
    __builtin_amdgcn_global_load_lds((const __attribute__((address_space(1))) void*)g,
                                     (__attribute__((address_space(3))) void*)l, 16, 0, 0);
}

// st_16x32 subtiled swizzle for a [R][64] bf16 tile staged as 16x32 subtiles.
__device__ __forceinline__ int swz(int row, int col) {
    return ((row >> 4) * 2 + (col >> 5)) * 512 + (row & 15) * 32 +
           ((col & 31) ^ ((row & 8) ? 16 : 0));
}

// ---------------- convert fp32 -> bf16 (flat) ----------------
__global__ __launch_bounds__(256) void cvt_kernel(const float* __restrict__ in,
                                                  u16* __restrict__ out, long n) {
    long i = ((long)blockIdx.x * blockDim.x + threadIdx.x) * 4;
    if (i + 3 < n) {
        float4 v = *(const float4*)&in[i];
        __align__(8) u16 r[4] = {f2bf(v.x), f2bf(v.y), f2bf(v.z), f2bf(v.w)};
        *(int2*)&out[i] = *(const int2*)r;
    }
}

// ---------------- transpose (+convert) -> bf16 ----------------
template <int INF32>
__global__ __launch_bounds__(256) void transpose_to_bf16(const void* __restrict__ in,
                                                         u16* __restrict__ out, int R, int C,
                                                         long inB, long outB) {
    __shared__ float tile[32][33];
    const long zi = (long)blockIdx.z * inB;
    const long zo = (long)blockIdx.z * outB;
    const int c0 = blockIdx.x * 32, r0 = blockIdx.y * 32;
    const int tx = threadIdx.x & 31;
    const int ty = threadIdx.x >> 5;  // 0..7
#pragma unroll
    for (int i = 0; i < 32; i += 8) {
        long idx = zi + (long)(r0 + ty + i) * C + c0 + tx;
        float v = INF32 ? ((const float*)in)[idx] : bf2f(((const u16*)in)[idx]);
        tile[ty + i][tx] = v;
    }
    __syncthreads();
#pragma unroll
    for (int i = 0; i < 32; i += 8) {
        out[zo + (long)(c0 + ty + i) * R + r0 + tx] = f2bf(tile[tx][ty + i]);
    }
}

// ---------------- 256x256 NT bf16 MFMA GEMM, phase-pipelined counted-vmcnt ----------
// C[M,N] = act(scale * (A[M,K] @ B[N,K]^T) + bias) [* rscale(row)]
// act: 0=none 1=relu 2=exp(x-32)
// 8 waves (2Mx4N), BK=64, 128KB double-buffered LDS, st_16x32 swizzle.
// Staging split into 4 chunks/tile interleaved with 4 MFMA phases; A-frag
// read-ahead by one phase; steady-state wait vmcnt(2); 2 barriers per K-tile.
// Non-symm: column-major block order within each XCD chunk (A-panels stay
// L2-resident; B streamed once) -> kills the ~3x FETCH overfetch.
// symm: balanced triangle (batch == XCD); mirror tile assembled in LDS
// (overlays staging buffers) and written back coalesced -> no RFO scatter.
template <int OUTBF>
__global__ __launch_bounds__(512, 2) void gemm_nt(const u16* __restrict__ A,
                                                  const u16* __restrict__ Bm,
                                                  void* __restrict__ Cout, int M, int N, int K,
                                                  long sA, long sB, long sC,
                                                  const float* __restrict__ bias, int act,
                                                  float scale, int symm,
                                                  const float* __restrict__ rscale) {
    int bx, by, zz;
    if (symm) {
        const int q = gridDim.x >> 3;
        const int orig = blockIdx.x;
        const int wgid = (orig & 7) * q + (orig >> 3);
        const int NB = N >> 8;
        const int nTri = (NB * (NB + 1)) >> 1;
        zz = wgid / nTri;
        int t = wgid - zz * nTri;
        by = 0;
        int rem = NB;
        while (t >= rem) {
            t -= rem;
            --rem;
            ++by;
        }
        bx = by + t;
    } else {
        const int nx = gridDim.x;
        const int nwg = nx * gridDim.y;
        const int orig = blockIdx.y * nx + blockIdx.x;
        const int q = nwg >> 3, r = nwg & 7, xcd = orig & 7, o8 = orig >> 3;
        const int wgid = (xcd < r ? xcd * (q + 1) : r * (q + 1) + (xcd - r) * q) + o8;
        if (r == 0 && (q % nx) == 0) {
            // column-major within the XCD's row-strip: A-panels L2-resident
            const int rpc = q / nx;  // block-rows per XCD chunk
            const int o = wgid - xcd * q;
            by = xcd * rpc + (o % rpc);
            bx = o / rpc;
        } else {
            bx = wgid % nx;
            by = wgid / nx;
        }
        zz = blockIdx.z;
    }

    // SM: As(32768 shorts) + Bs(32768); mirror tile T (256x264) overlays all.
    __shared__ __align__(16) u16 SM[67584];
    u16(*As)[256 * 64] = (u16(*)[256 * 64])SM;
    u16(*Bs)[256 * 64] = (u16(*)[256 * 64])(SM + 32768);
    u16* T = SM;
    const int tid = threadIdx.x;  // 0..511
    const int lane = tid & 63;
    const int wid = tid >> 6;  // 0..7
    const int wr = wid >> 2;   // 0..1
    const int wc = wid & 3;    // 0..3
    const int l15 = lane & 15, lg = lane >> 4;
    const long zA = (long)zz * sA;
    const long zB = (long)zz * sB;
    const long zC = (long)zz * sC;
    const int m0 = by * 256, n0 = bx * 256;
    const u16* Ab = A + zA + (long)m0 * K;
    const u16* Bb = Bm + zB + (long)n0 * K;
    const int nt = K >> 6;

    f32x4 acc[8][4] = {};

    // one chunk = 2 gld16/thread (1KB/wave into A + 1KB into B); 4 chunks/tile.
    auto stage_chunk = [&](int t, int b, int j) {
        const int c = j * 512 + tid;
        const int s = c >> 6, r = (c >> 2) & 15;
        const int row = (s >> 1) * 16 + r;
        const int col = (s & 1) * 32 + (((c & 3) * 8) ^ ((r & 8) ? 16 : 0));
        gld16(Ab + (long)row * K + t * 64 + col, &As[b][c * 8]);
        gld16(Bb + (long)row * K + t * 64 + col, &Bs[b][c * 8]);
    };

#pragma unroll
    for (int j = 0; j < 4; ++j) stage_chunk(0, 0, j);
    if (nt > 1) {
        stage_chunk(1, 1, 0);
        asm volatile("s_waitcnt vmcnt(2)" ::: "memory");
    } else {
        asm volatile("s_waitcnt vmcnt(0)" ::: "memory");
    }
    __builtin_amdgcn_s_barrier();

    for (int t = 0; t < nt; ++t) {
        const int cur = t & 1;
        bf16x8 bf[4][2];
#pragma unroll
        for (int n = 0; n < 4; ++n)
#pragma unroll
            for (int kk = 0; kk < 2; ++kk)
                bf[n][kk] = *(const bf16x8*)&Bs[cur][swz(wc * 64 + n * 16 + l15, kk * 32 + lg * 8)];
        bf16x8 af[2][2][2];
#pragma unroll
        for (int mi = 0; mi < 2; ++mi)
#pragma unroll
            for (int kk = 0; kk < 2; ++kk)
                af[0][mi][kk] =
                    *(const bf16x8*)&As[cur][swz(wr * 128 + mi * 16 + l15, kk * 32 + lg * 8)];
#pragma unroll
        for (int mg = 0; mg < 4; ++mg) {
            if (mg < 3) {
#pragma unroll
                for (int mi = 0; mi < 2; ++mi)
#pragma unroll
                    for (int kk = 0; kk < 2; ++kk)
                        af[(mg + 1) & 1][mi][kk] = *(const bf16x8*)&As[cur][swz(
                            wr * 128 + (mg + 1) * 32 + mi * 16 + l15, kk * 32 + lg * 8)];
                if (t + 1 < nt) stage_chunk(t + 1, cur ^ 1, mg + 1);
            }
            __builtin_amdgcn_s_setprio(1);
#pragma unroll
            for (int mi = 0; mi < 2; ++mi)
#pragma unroll
                for (int n = 0; n < 4; ++n)
#pragma unroll
                    for (int kk = 0; kk < 2; ++kk)
                        acc[mg * 2 + mi][n] = __builtin_amdgcn_mfma_f32_16x16x32_bf16(
                            af[mg & 1][mi][kk], bf[n][kk], acc[mg * 2 + mi][n], 0, 0, 0);
            __builtin_amdgcn_s_setprio(0);
        }
        // transition: free buf cur, prefetch chunk0 of tile t+2 into it, publish cur^1
        __builtin_amdgcn_s_barrier();
        if (t + 2 < nt) {
            stage_chunk(t + 2, cur, 0);
            asm volatile("s_waitcnt vmcnt(2)" ::: "memory");
        } else {
            asm volatile("s_waitcnt vmcnt(0)" ::: "memory");
        }
        __builtin_amdgcn_s_barrier();
    }

    const int mirror = symm && (bx > by);
#pragma unroll
    for (int n = 0; n < 4; ++n) {
        const int col = n0 + wc * 64 + n * 16 + l15;
        const float bv = bias ? bias[col] : 0.0f;
#pragma unroll
        for (int m = 0; m < 8; ++m) {
            const int rowb = m0 + wr * 128 + m * 16 + lg * 4;
            float v[4];
#pragma unroll
            for (int r = 0; r < 4; ++r) {
                float f = acc[m][n][r] * scale + bv;
                if (act == 1)
                    f = fmaxf(f, 0.0f);
                else if (act == 2)
                    f = __expf(f - 32.0f);
                if (rscale) f *= rscale[(long)zz * M + rowb + r];
                v[r] = f;
                if (OUTBF)
                    ((u16*)Cout)[zC + (long)(rowb + r) * N + col] = f2bf(f);
                else
                    ((float*)Cout)[zC + (long)(rowb + r) * N + col] = f;
            }
            if (mirror) {
                if (OUTBF) {
                    // stage transposed element block into LDS tile T[col][row]
                    const int cl = wc * 64 + n * 16 + l15;
                    const int rl = wr * 128 + m * 16 + lg * 4;
                    __align__(8) u16 tv[4] = {f2bf(v[0]), f2bf(v[1]), f2bf(v[2]), f2bf(v[3])};
                    *(int2*)&T[cl * 264 + rl] = *(const int2*)tv;
                } else {
                    *(float4*)&((float*)Cout)[zC + (long)col * N + rowb] =
                        make_float4(v[0], v[1], v[2], v[3]);
                }
            }
        }
    }
    if (mirror && OUTBF) {
        __builtin_amdgcn_s_barrier();
#pragma unroll
        for (int i = 0; i < 16; ++i) {
            const int c = i * 512 + tid;  // 8192 16B-chunks: 256 rows x 32
            const int tr = c >> 5, tc = c & 31;
            *(int4*)&((u16*)Cout)[zC + (long)(n0 + tr) * N + m0 + tc * 8] =
                *(const int4*)&T[tr * 264 + tc * 8];
        }
    }
}

// ---------------- LayerNorm, wave-per-row (bf16 in/out, in-place) ----------------
template <int CH>
__global__ __launch_bounds__(256) void ln_wave(u16* __restrict__ x, const float* __restrict__ g,
                                               const float* __restrict__ be) {
    const int lane = threadIdx.x & 63;
    const int wid = threadIdx.x >> 6;
    const long row = (long)blockIdx.x * 4 + wid;
    u16* p = x + row * (CH * 512);
    __align__(16) u16 raw[CH][8];
    float s = 0.f, ss = 0.f;
#pragma unroll
    for (int c = 0; c < CH; ++c) {
        *(int4*)raw[c] = *(const int4*)&p[(c * 64 + lane) * 8];
#pragma unroll
        for (int j = 0; j < 8; ++j) {
            float f = bf2f(raw[c][j]);
            s += f;
            ss += f * f;
        }
    }
#pragma unroll
    for (int o = 1; o < 64; o <<= 1) {
        s += __shfl_xor(s, o);
        ss += __shfl_xor(ss, o);
    }
    const float inv = 1.0f / (float)(CH * 512);
    const float mu = s * inv;
    const float var = ss * inv - mu * mu;
    const float rs = rsqrtf(var + 1e-5f);
#pragma unroll
    for (int c = 0; c < CH; ++c) {
        const int base = (c * 64 + lane) * 8;
        float4 g0 = *(const float4*)&g[base];
        float4 g1 = *(const float4*)&g[base + 4];
        float4 b0 = *(const float4*)&be[base];
        float4 b1 = *(const float4*)&be[base + 4];
        float gv[8] = {g0.x, g0.y, g0.z, g0.w, g1.x, g1.y, g1.z, g1.w};
        float bv[8] = {b0.x, b0.y, b0.z, b0.w, b1.x, b1.y, b1.z, b1.w};
#pragma unroll
        for (int j = 0; j < 8; ++j)
            raw[c][j] = f2bf((bf2f(raw[c][j]) - mu) * rs * gv[j] + bv[j]);
        *(int4*)&p[base] = *(const int4*)raw[c];
    }
}

// ---------------- normalize: weights = E/rowsum -> d_out fp32, rowInv ----------------
__global__ __launch_bounds__(256) void norm_wave(const u16* __restrict__ e,
                                                 float* __restrict__ outw,
                                                 float* __restrict__ rowInv) {
    const int lane = threadIdx.x & 63;
    const int wid = threadIdx.x >> 6;
    const long row = (long)blockIdx.x * 4 + wid;
    const u16* p = e + row * 2048;
    float v[4][8];
    float s = 0.f;
#pragma unroll
    for (int c = 0; c < 4; ++c) {
        __align__(16) u16 raw[8];
        *(int4*)raw = *(const int4*)&p[(c * 64 + lane) * 8];
#pragma unroll
        for (int j = 0; j < 8; ++j) {
            v[c][j] = bf2f(raw[j]);
            s += v[c][j];
        }
    }
#pragma unroll
    for (int o = 1; o < 64; o <<= 1) s += __shfl_xor(s, o);
    const float inv = 1.0f / s;
    if (lane == 0) rowInv[row] = inv;
    float* q = outw + row * 2048;
#pragma unroll
    for (int c = 0; c < 4; ++c) {
        const int base = (c * 64 + lane) * 8;
        float4 o0 = make_float4(v[c][0] * inv, v[c][1] * inv, v[c][2] * inv, v[c][3] * inv);
        float4 o1 = make_float4(v[c][4] * inv, v[c][5] * inv, v[c][6] * inv, v[c][7] * inv);
        *(float4*)&q[base] = o0;
        *(float4*)&q[base + 4] = o1;
    }
}

// ---------------- head: attended(bf16) @ WhT + bh -> gates -> log ----------------
__global__ __launch_bounds__(256) void head_kernel(const u16* __restrict__ A,
                                                   const u16* __restrict__ WhT,
                                                   const float* __restrict__ bh,
                                                   const float* __restrict__ prior,
                                                   const float* __restrict__ ag,
                                                   const float* __restrict__ og,
                                                   float* __restrict__ out) {
    __shared__ __align__(16) u16 As2[128 * 64];
    __shared__ __align__(16) u16 Bs2[64 * 64];
    const int tid = threadIdx.x;
    const int lane = tid & 63;
    const int wid = tid >> 6;
    const int l15 = lane & 15, lg = lane >> 4;
    const int m0 = blockIdx.x * 128;
    const int srow = tid >> 3, scol = (tid & 7) * 8;
    const u16* pa = A + (long)(m0 + srow) * 1024 + scol;
    const u16* pb = WhT + (long)srow * 1024 + scol;

    f32x4 acc[2][4] = {};
    for (int k0 = 0; k0 < 1024; k0 += 64) {
#pragma unroll
        for (int i = 0; i < 4; ++i) gld16(pa + (long)i * 32 * 1024 + k0, &As2[i * 2048 + tid * 8]);
#pragma unroll
        for (int i = 0; i < 2; ++i) gld16(pb + (long)i * 32 * 1024 + k0, &Bs2[i * 2048 + tid * 8]);
        __syncthreads();
#pragma unroll
        for (int kk = 0; kk < 2; ++kk) {
            bf16x8 af[2], bfr[4];
#pragma unroll
            for (int m = 0; m < 2; ++m)
                af[m] = *(const bf16x8*)&As2[(wid * 32 + m * 16 + l15) * 64 + kk * 32 + lg * 8];
#pragma unroll
            for (int n = 0; n < 4; ++n)
                bfr[n] = *(const bf16x8*)&Bs2[(n * 16 + l15) * 64 + kk * 32 + lg * 8];
#pragma unroll
            for (int m = 0; m < 2; ++m)
#pragma unroll
                for (int n = 0; n < 4; ++n)
                    acc[m][n] =
                        __builtin_amdgcn_mfma_f32_16x16x32_bf16(af[m], bfr[n], acc[m][n], 0, 0, 0);
        }
        __syncthreads();
    }

#pragma unroll
    for (int n = 0; n < 4; ++n) {
        const int col = n * 16 + l15;
        const float bhv = bh[col];
        const float agv = ag[col];
        const float ogv = og[col];
#pragma unroll
        for (int m = 0; m < 2; ++m) {
#pragma unroll
            for (int r = 0; r < 4; ++r) {
                const int row = m0 + wid * 32 + m * 16 + lg * 4 + r;
                const float logit = acc[m][n][r] + bhv;
                const int b = row >> 11;
                const float sp = 1.f / (1.f + expf(-prior[b * 64 + col]));
                const float sl = 1.f / (1.f + expf(-logit));
                const float av = fminf(sl, sp) * agv;
                const float ov = fmaxf(sl, sp) * ogv;
                out[(long)row * 64 + col] = logf((av + ov) * 0.5f + 1e-10f);
            }
        }
    }
}

extern "C" void kernel_launch(void* const* d_in, const int* in_sizes, int n_in, void* d_out,
                              int out_size, void* d_ws, size_t ws_size, hipStream_t stream) {
    const float* emb = (const float*)d_in[0];
    const float* prior = (const float*)d_in[1];
    const float* W1 = (const float*)d_in[2];
    const float* b1 = (const float*)d_in[3];
    const float* g1 = (const float*)d_in[4];
    const float* be1 = (const float*)d_in[5];
    const float* W2 = (const float*)d_in[6];
    const float* b2 = (const float*)d_in[7];
    const float* g2 = (const float*)d_in[8];
    const float* be2 = (const float*)d_in[9];
    const float* Wh = (const float*)d_in[10];
    const float* bh = (const float*)d_in[11];
    const float* ag = (const float*)d_in[12];
    const float* og = (const float*)d_in[13];

    const int Bn = 8, S = 2048, DIN = 1024, H1 = 2048, H2 = 1024, Cc = 64;
    const int M = Bn * S;  // 16384

    char* ws = (char*)d_ws;
    size_t off = 0;
    auto alloc = [&](size_t b) {
        size_t o = off;
        off += (b + 255) & ~(size_t)255;
        return o;
    };
    // Live-range-shared regions (peak ~136.2 MB, under the proven 277 MB):
    //   R0 (64MB): h (steps 4-6)      then attnb/E (steps 9-11)
    //   R1 (32MB): embb (steps 1-4)   then featT (steps 8-11)
    //   R2 (32MB): feat (steps 6-9)   then attd (steps 11-12)
    char* R0 = ws + alloc((size_t)M * H1 * 2);
    char* R1 = ws + alloc((size_t)M * DIN * 2);
    char* R2 = ws + alloc((size_t)M * H2 * 2);
    u16* W1t = (u16*)(ws + alloc((size_t)H1 * DIN * 2));
    u16* W2t = (u16*)(ws + alloc((size_t)H2 * H1 * 2));
    u16* WhT = (u16*)(ws + alloc((size_t)Cc * H2 * 2));
    float* rowInv = (float*)(ws + alloc((size_t)M * 4));

    u16* h = (u16*)R0;
    u16* attnb = (u16*)R0;
    u16* embb = (u16*)R1;
    u16* featT = (u16*)R1;
    u16* feat = (u16*)R2;
    u16* attd = (u16*)R2;

    float* out_logits = (float*)d_out;
    float* out_attn = out_logits + (size_t)M * Cc;

    // 1. embeddings -> bf16
    cvt_kernel<<<(int)(((long)M * DIN) / 1024), 256, 0, stream>>>(emb, embb, (long)M * DIN);
    // 2. W1 [DIN][H1] -> W1t [H1][DIN]
    transpose_to_bf16<1><<<dim3(H1 / 32, DIN / 32, 1), 256, 0, stream>>>(W1, W1t, DIN, H1, 0, 0);
    // 3. W2 [H1][H2] -> W2t [H2][H1]
    transpose_to_bf16<1><<<dim3(H2 / 32, H1 / 32, 1), 256, 0, stream>>>(W2, W2t, H1, H2, 0, 0);
    // 3b. Wh [H2][C] -> WhT [C][H2]
    transpose_to_bf16<1><<<dim3(Cc / 32, H2 / 32, 1), 256, 0, stream>>>(Wh, WhT, H2, Cc, 0, 0);
    // 4. h = relu(emb @ W1 + b1)   [M,H1] bf16
    gemm_nt<1><<<dim3(H1 / 256, M / 256, 1), 512, 0, stream>>>(embb, W1t, h, M, H1, DIN, 0, 0, 0,
                                                               b1, 1, 1.0f, 0, nullptr);
    // 5. LN1 (wave-per-row)
    ln_wave<4><<<M / 4, 256, 0, stream>>>(h, g1, be1);
    // 6. feat = relu(h @ W2 + b2)  [M,H2] bf16
    gemm_nt<1><<<dim3(H2 / 256, M / 256, 1), 512, 0, stream>>>(h, W2t, feat, M, H2, H1, 0, 0, 0,
                                                               b2, 1, 1.0f, 0, nullptr);
    // 7. LN2
    ln_wave<2><<<M / 4, 256, 0, stream>>>(feat, g2, be2);
    // 8. featT per batch: [S][H2] -> [H2][S]
    transpose_to_bf16<0><<<dim3(H2 / 32, S / 32, Bn), 256, 0, stream>>>(
        feat, featT, S, H2, (long)S * H2, (long)H2 * S);
    // 9. E = exp(feat@feat^T/32 - 32) bf16 -> attnb, balanced triangle + LDS mirror
    {
        const int NB = S / 256;              // 8
        const int nTri = NB * (NB + 1) / 2;  // 36
        gemm_nt<1><<<dim3(nTri * Bn, 1, 1), 512, 0, stream>>>(
            feat, feat, attnb, S, S, H2, (long)S * H2, (long)S * H2, (long)S * S, nullptr,
            /*act=*/2, 0.03125f, /*symm=*/1, nullptr);
    }
    // 10. normalize: attention weights fp32 -> d_out, rowInv for attended
    norm_wave<<<M / 4, 256, 0, stream>>>(attnb, out_attn, rowInv);
    // 11. attended = (E @ featT) * rowInv   [S,H2] bf16 per batch
    gemm_nt<1><<<dim3(H2 / 256, S / 256, Bn), 512, 0, stream>>>(attnb, featT, attd, S, H2, S,
                                                                (long)S * S, (long)H2 * S,
                                                                (long)S * H2, nullptr, 0, 1.0f, 0,
                                                                rowInv);
    // 12. head + logic gates + log (MFMA)
    head_kernel<<<M / 128, 256, 0, stream>>>(attd, WhT, bh, prior, ag, og, out_logits);
}

// Round 18
// 450.509 us; speedup vs baseline: 1.0539x; 1.0064x over previous
//
#include <hip/hip_runtime.h>

typedef unsigned short u16;
typedef __bf16 bf16x8 __attribute__((ext_vector_type(8)));
typedef float f32x4 __attribute__((ext_vector_type(4)));

__device__ __forceinline__ u16 f2bf(float f) {
    unsigned u = __float_as_uint(f);
    u = (u + 0x7FFFu + ((u >> 16) & 1u)) >> 16;
    return (u16)u;
}
__device__ __forceinline__ float bf2f(u16 h) {
    return __uint_as_float(((unsigned)h) << 16);
}

// async global -> LDS, 16B per lane
__device__ __forceinline__ void gld16(const u16* g, u16* l) {
    __builtin_amdgcn_global_load_lds((const __attribute__((address_space(1))) void*)g,
                                     (__attribute__((address_space(3))) void*)l, 16, 0, 0);
}

// st_16x32 subtiled swizzle for a [R][64] bf16 tile staged as 16x32 subtiles.
__device__ __forceinline__ int swz(int row, int col) {
    return ((row >> 4) * 2 + (col >> 5)) * 512 + (row & 15) * 32 +
           ((col & 31) ^ ((row & 8) ? 16 : 0));
}

// ---------------- convert fp32 -> bf16 (flat) ----------------
__global__ __launch_bounds__(256) void cvt_kernel(const float* __restrict__ in,
                                                  u16* __restrict__ out, long n) {
    long i = ((long)blockIdx.x * blockDim.x + threadIdx.x) * 4;
    if (i + 3 < n) {
        float4 v = *(const float4*)&in[i];
        __align__(8) u16 r[4] = {f2bf(v.x), f2bf(v.y), f2bf(v.z), f2bf(v.w)};
        *(int2*)&out[i] = *(const int2*)r;
    }
}

// ---------------- transpose (+convert) -> bf16 ----------------
template <int INF32>
__global__ __launch_bounds__(256) void transpose_to_bf16(const void* __restrict__ in,
                                                         u16* __restrict__ out, int R, int C,
                                                         long inB, long outB) {
    __shared__ float tile[32][33];
    const long zi = (long)blockIdx.z * inB;
    const long zo = (long)blockIdx.z * outB;
    const int c0 = blockIdx.x * 32, r0 = blockIdx.y * 32;
    const int tx = threadIdx.x & 31;
    const int ty = threadIdx.x >> 5;  // 0..7
#pragma unroll
    for (int i = 0; i < 32; i += 8) {
        long idx = zi + (long)(r0 + ty + i) * C + c0 + tx;
        float v = INF32 ? ((const float*)in)[idx] : bf2f(((const u16*)in)[idx]);
        tile[ty + i][tx] = v;
    }
    __syncthreads();
#pragma unroll
    for (int i = 0; i < 32; i += 8) {
        out[zo + (long)(c0 + ty + i) * R + r0 + tx] = f2bf(tile[tx][ty + i]);
    }
}

// ---------------- 256x256 NT bf16 MFMA GEMM, phase-pipelined counted-vmcnt ----------
// C[M,N] = act(scale * (A[M,K] @ B[N,K]^T) + bias) [* rscale(row)]
// act: 0=none 1=relu 2=exp(x-32)
// 8 waves (2Mx4N), BK=64, 128KB double-buffered LDS, st_16x32 swizzle.
// Staging split into 4 chunks/tile interleaved with 4 MFMA phases; A-frag
// read-ahead by one phase; steady-state wait vmcnt(2); 2 barriers per K-tile.
// Non-symm: column-major block order within each XCD chunk (A-panels stay
// L2-resident; B streamed once) -> kills the ~3x FETCH overfetch.
// symm: balanced triangle (batch == XCD); mirror tile assembled in LDS
// (overlays staging buffers) and written back coalesced -> no RFO scatter.
template <int OUTBF>
__global__ __launch_bounds__(512, 2) void gemm_nt(const u16* __restrict__ A,
                                                  const u16* __restrict__ Bm,
                                                  void* __restrict__ Cout, int M, int N, int K,
                                                  long sA, long sB, long sC,
                                                  const float* __restrict__ bias, int act,
                                                  float scale, int symm,
                                                  const float* __restrict__ rscale) {
    int bx, by, zz;
    if (symm) {
        const int q = gridDim.x >> 3;
        const int orig = blockIdx.x;
        const int wgid = (orig & 7) * q + (orig >> 3);
        const int NB = N >> 8;
        const int nTri = (NB * (NB + 1)) >> 1;
        zz = wgid / nTri;
        int t = wgid - zz * nTri;
        by = 0;
        int rem = NB;
        while (t >= rem) {
            t -= rem;
            --rem;
            ++by;
        }
        bx = by + t;
    } else {
        const int nx = gridDim.x;
        const int nwg = nx * gridDim.y;
        const int orig = blockIdx.y * nx + blockIdx.x;
        const int q = nwg >> 3, r = nwg & 7, xcd = orig & 7, o8 = orig >> 3;
        const int wgid = (xcd < r ? xcd * (q + 1) : r * (q + 1) + (xcd - r) * q) + o8;
        if (r == 0 && (q % nx) == 0) {
            // column-major within the XCD's row-strip: A-panels L2-resident
            const int rpc = q / nx;  // block-rows per XCD chunk
            const int o = wgid - xcd * q;
            by = xcd * rpc + (o % rpc);
            bx = o / rpc;
        } else {
            bx = wgid % nx;
            by = wgid / nx;
        }
        zz = blockIdx.z;
    }

    // SM: As(32768 shorts) + Bs(32768); mirror tile T (256x264) overlays all.
    __shared__ __align__(16) u16 SM[67584];
    u16(*As)[256 * 64] = (u16(*)[256 * 64])SM;
    u16(*Bs)[256 * 64] = (u16(*)[256 * 64])(SM + 32768);
    u16* T = SM;
    const int tid = threadIdx.x;  // 0..511
    const int lane = tid & 63;
    const int wid = tid >> 6;  // 0..7
    const int wr = wid >> 2;   // 0..1
    const int wc = wid & 3;    // 0..3
    const int l15 = lane & 15, lg = lane >> 4;
    const long zA = (long)zz * sA;
    const long zB = (long)zz * sB;
    const long zC = (long)zz * sC;
    const int m0 = by * 256, n0 = bx * 256;
    const u16* Ab = A + zA + (long)m0 * K;
    const u16* Bb = Bm + zB + (long)n0 * K;
    const int nt = K >> 6;

    f32x4 acc[8][4] = {};

    // one chunk = 2 gld16/thread (1KB/wave into A + 1KB into B); 4 chunks/tile.
    auto stage_chunk = [&](int t, int b, int j) {
        const int c = j * 512 + tid;
        const int s = c >> 6, r = (c >> 2) & 15;
        const int row = (s >> 1) * 16 + r;
        const int col = (s & 1) * 32 + (((c & 3) * 8) ^ ((r & 8) ? 16 : 0));
        gld16(Ab + (long)row * K + t * 64 + col, &As[b][c * 8]);
        gld16(Bb + (long)row * K + t * 64 + col, &Bs[b][c * 8]);
    };

#pragma unroll
    for (int j = 0; j < 4; ++j) stage_chunk(0, 0, j);
    if (nt > 1) {
        stage_chunk(1, 1, 0);
        asm volatile("s_waitcnt vmcnt(2)" ::: "memory");
    } else {
        asm volatile("s_waitcnt vmcnt(0)" ::: "memory");
    }
    __builtin_amdgcn_s_barrier();

    for (int t = 0; t < nt; ++t) {
        const int cur = t & 1;
        bf16x8 bf[4][2];
#pragma unroll
        for (int n = 0; n < 4; ++n)
#pragma unroll
            for (int kk = 0; kk < 2; ++kk)
                bf[n][kk] = *(const bf16x8*)&Bs[cur][swz(wc * 64 + n * 16 + l15, kk * 32 + lg * 8)];
        bf16x8 af[2][2][2];
#pragma unroll
        for (int mi = 0; mi < 2; ++mi)
#pragma unroll
            for (int kk = 0; kk < 2; ++kk)
                af[0][mi][kk] =
                    *(const bf16x8*)&As[cur][swz(wr * 128 + mi * 16 + l15, kk * 32 + lg * 8)];
#pragma unroll
        for (int mg = 0; mg < 4; ++mg) {
            if (mg < 3) {
#pragma unroll
                for (int mi = 0; mi < 2; ++mi)
#pragma unroll
                    for (int kk = 0; kk < 2; ++kk)
                        af[(mg + 1) & 1][mi][kk] = *(const bf16x8*)&As[cur][swz(
                            wr * 128 + (mg + 1) * 32 + mi * 16 + l15, kk * 32 + lg * 8)];
                if (t + 1 < nt) stage_chunk(t + 1, cur ^ 1, mg + 1);
            }
            __builtin_amdgcn_s_setprio(1);
#pragma unroll
            for (int mi = 0; mi < 2; ++mi)
#pragma unroll
                for (int n = 0; n < 4; ++n)
#pragma unroll
                    for (int kk = 0; kk < 2; ++kk)
                        acc[mg * 2 + mi][n] = __builtin_amdgcn_mfma_f32_16x16x32_bf16(
                            af[mg & 1][mi][kk], bf[n][kk], acc[mg * 2 + mi][n], 0, 0, 0);
            __builtin_amdgcn_s_setprio(0);
        }
        // transition: free buf cur, prefetch chunk0 of tile t+2 into it, publish cur^1
        __builtin_amdgcn_s_barrier();
        if (t + 2 < nt) {
            stage_chunk(t + 2, cur, 0);
            asm volatile("s_waitcnt vmcnt(2)" ::: "memory");
        } else {
            asm volatile("s_waitcnt vmcnt(0)" ::: "memory");
        }
        __builtin_amdgcn_s_barrier();
    }

    const int mirror = symm && (bx > by);
#pragma unroll
    for (int n = 0; n < 4; ++n) {
        const int col = n0 + wc * 64 + n * 16 + l15;
        const float bv = bias ? bias[col] : 0.0f;
#pragma unroll
        for (int m = 0; m < 8; ++m) {
            const int rowb = m0 + wr * 128 + m * 16 + lg * 4;
            float v[4];
#pragma unroll
            for (int r = 0; r < 4; ++r) {
                float f = acc[m][n][r] * scale + bv;
                if (act == 1)
                    f = fmaxf(f, 0.0f);
                else if (act == 2)
                    f = __expf(f - 32.0f);
                if (rscale) f *= rscale[(long)zz * M + rowb + r];
                v[r] = f;
                if (OUTBF)
                    ((u16*)Cout)[zC + (long)(rowb + r) * N + col] = f2bf(f);
                else
                    ((float*)Cout)[zC + (long)(rowb + r) * N + col] = f;
            }
            if (mirror) {
                if (OUTBF) {
                    // stage transposed element block into LDS tile T[col][row]
                    const int cl = wc * 64 + n * 16 + l15;
                    const int rl = wr * 128 + m * 16 + lg * 4;
                    __align__(8) u16 tv[4] = {f2bf(v[0]), f2bf(v[1]), f2bf(v[2]), f2bf(v[3])};
                    *(int2*)&T[cl * 264 + rl] = *(const int2*)tv;
                } else {
                    *(float4*)&((float*)Cout)[zC + (long)col * N + rowb] =
                        make_float4(v[0], v[1], v[2], v[3]);
                }
            }
        }
    }
    if (mirror && OUTBF) {
        __builtin_amdgcn_s_barrier();
#pragma unroll
        for (int i = 0; i < 16; ++i) {
            const int c = i * 512 + tid;  // 8192 16B-chunks: 256 rows x 32
            const int tr = c >> 5, tc = c & 31;
            *(int4*)&((u16*)Cout)[zC + (long)(n0 + tr) * N + m0 + tc * 8] =
                *(const int4*)&T[tr * 264 + tc * 8];
        }
    }
}

// ---------------- LayerNorm, wave-per-row (bf16 in/out, in-place) ----------------
template <int CH>
__global__ __launch_bounds__(256) void ln_wave(u16* __restrict__ x, const float* __restrict__ g,
                                               const float* __restrict__ be) {
    const int lane = threadIdx.x & 63;
    const int wid = threadIdx.x >> 6;
    const long row = (long)blockIdx.x * 4 + wid;
    u16* p = x + row * (CH * 512);
    __align__(16) u16 raw[CH][8];
    float s = 0.f, ss = 0.f;
#pragma unroll
    for (int c = 0; c < CH; ++c) {
        *(int4*)raw[c] = *(const int4*)&p[(c * 64 + lane) * 8];
#pragma unroll
        for (int j = 0; j < 8; ++j) {
            float f = bf2f(raw[c][j]);
            s += f;
            ss += f * f;
        }
    }
#pragma unroll
    for (int o = 1; o < 64; o <<= 1) {
        s += __shfl_xor(s, o);
        ss += __shfl_xor(ss, o);
    }
    const float inv = 1.0f / (float)(CH * 512);
    const float mu = s * inv;
    const float var = ss * inv - mu * mu;
    const float rs = rsqrtf(var + 1e-5f);
#pragma unroll
    for (int c = 0; c < CH; ++c) {
        const int base = (c * 64 + lane) * 8;
        float4 g0 = *(const float4*)&g[base];
        float4 g1 = *(const float4*)&g[base + 4];
        float4 b0 = *(const float4*)&be[base];
        float4 b1 = *(const float4*)&be[base + 4];
        float gv[8] = {g0.x, g0.y, g0.z, g0.w, g1.x, g1.y, g1.z, g1.w};
        float bv[8] = {b0.x, b0.y, b0.z, b0.w, b1.x, b1.y, b1.z, b1.w};
#pragma unroll
        for (int j = 0; j < 8; ++j)
            raw[c][j] = f2bf((bf2f(raw[c][j]) - mu) * rs * gv[j] + bv[j]);
        *(int4*)&p[base] = *(const int4*)raw[c];
    }
}

// ---------------- normalize: weights = E/rowsum -> d_out fp32, rowInv ----------------
__global__ __launch_bounds__(256) void norm_wave(const u16* __restrict__ e,
                                                 float* __restrict__ outw,
                                                 float* __restrict__ rowInv) {
    const int lane = threadIdx.x & 63;
    const int wid = threadIdx.x >> 6;
    const long row = (long)blockIdx.x * 4 + wid;
    const u16* p = e + row * 2048;
    float v[4][8];
    float s = 0.f;
#pragma unroll
    for (int c = 0; c < 4; ++c) {
        __align__(16) u16 raw[8];
        *(int4*)raw = *(const int4*)&p[(c * 64 + lane) * 8];
#pragma unroll
        for (int j = 0; j < 8; ++j) {
            v[c][j] = bf2f(raw[j]);
            s += v[c][j];
        }
    }
#pragma unroll
    for (int o = 1; o < 64; o <<= 1) s += __shfl_xor(s, o);
    const float inv = 1.0f / s;
    if (lane == 0) rowInv[row] = inv;
    float* q = outw + row * 2048;
#pragma unroll
    for (int c = 0; c < 4; ++c) {
        const int base = (c * 64 + lane) * 8;
        float4 o0 = make_float4(v[c][0] * inv, v[c][1] * inv, v[c][2] * inv, v[c][3] * inv);
        float4 o1 = make_float4(v[c][4] * inv, v[c][5] * inv, v[c][6] * inv, v[c][7] * inv);
        *(float4*)&q[base] = o0;
        *(float4*)&q[base + 4] = o1;
    }
}

// ---------------- head: attended(bf16) @ WhT + bh -> gates -> log ----------------
__global__ __launch_bounds__(256) void head_kernel(const u16* __restrict__ A,
                                                   const u16* __restrict__ WhT,
                                                   const float* __restrict__ bh,
                                                   const float* __restrict__ prior,
                                                   const float* __restrict__ ag,
                                                   const float* __restrict__ og,
                                                   float* __restrict__ out) {
    __shared__ __align__(16) u16 As2[128 * 64];
    __shared__ __align__(16) u16 Bs2[64 * 64];
    const int tid = threadIdx.x;
    const int lane = tid & 63;
    const int wid = tid >> 6;
    const int l15 = lane & 15, lg = lane >> 4;
    const int m0 = blockIdx.x * 128;
    const int srow = tid >> 3, scol = (tid & 7) * 8;
    const u16* pa = A + (long)(m0 + srow) * 1024 + scol;
    const u16* pb = WhT + (long)srow * 1024 + scol;

    f32x4 acc[2][4] = {};
    for (int k0 = 0; k0 < 1024; k0 += 64) {
#pragma unroll
        for (int i = 0; i < 4; ++i) gld16(pa + (long)i * 32 * 1024 + k0, &As2[i * 2048 + tid * 8]);
#pragma unroll
        for (int i = 0; i < 2; ++i) gld16(pb + (long)i * 32 * 1024 + k0, &Bs2[i * 2048 + tid * 8]);
        __syncthreads();
#pragma unroll
        for (int kk = 0; kk < 2; ++kk) {
            bf16x8 af[2], bfr[4];
#pragma unroll
            for (int m = 0; m < 2; ++m)
                af[m] = *(const bf16x8*)&As2[(wid * 32 + m * 16 + l15) * 64 + kk * 32 + lg * 8];
#pragma unroll
            for (int n = 0; n < 4; ++n)
                bfr[n] = *(const bf16x8*)&Bs2[(n * 16 + l15) * 64 + kk * 32 + lg * 8];
#pragma unroll
            for (int m = 0; m < 2; ++m)
#pragma unroll
                for (int n = 0; n < 4; ++n)
                    acc[m][n] =
                        __builtin_amdgcn_mfma_f32_16x16x32_bf16(af[m], bfr[n], acc[m][n], 0, 0, 0);
        }
        __syncthreads();
    }

#pragma unroll
    for (int n = 0; n < 4; ++n) {
        const int col = n * 16 + l15;
        const float bhv = bh[col];
        const float agv = ag[col];
        const float ogv = og[col];
#pragma unroll
        for (int m = 0; m < 2; ++m) {
#pragma unroll
            for (int r = 0; r < 4; ++r) {
                const int row = m0 + wid * 32 + m * 16 + lg * 4 + r;
                const float logit = acc[m][n][r] + bhv;
                const int b = row >> 11;
                const float sp = 1.f / (1.f + expf(-prior[b * 64 + col]));
                const float sl = 1.f / (1.f + expf(-logit));
                const float av = fminf(sl, sp) * agv;
                const float ov = fmaxf(sl, sp) * ogv;
                out[(long)row * 64 + col] = logf((av + ov) * 0.5f + 1e-10f);
            }
        }
    }
}

extern "C" void kernel_launch(void* const* d_in, const int* in_sizes, int n_in, void* d_out,
                              int out_size, void* d_ws, size_t ws_size, hipStream_t stream) {
    const float* emb = (const float*)d_in[0];
    const float* prior = (const float*)d_in[1];
    const float* W1 = (const float*)d_in[2];
    const float* b1 = (const float*)d_in[3];
    const float* g1 = (const float*)d_in[4];
    const float* be1 = (const float*)d_in[5];
    const float* W2 = (const float*)d_in[6];
    const float* b2 = (const float*)d_in[7];
    const float* g2 = (const float*)d_in[8];
    const float* be2 = (const float*)d_in[9];
    const float* Wh = (const float*)d_in[10];
    const float* bh = (const float*)d_in[11];
    const float* ag = (const float*)d_in[12];
    const float* og = (const float*)d_in[13];

    const int Bn = 8, S = 2048, DIN = 1024, H1 = 2048, H2 = 1024, Cc = 64;
    const int M = Bn * S;  // 16384

    char* ws = (char*)d_ws;
    size_t off = 0;
    auto alloc = [&](size_t b) {
        size_t o = off;
        off += (b + 255) & ~(size_t)255;
        return o;
    };
    // Live-range-shared regions (peak ~136.2 MB, under the proven 277 MB):
    //   R0 (64MB): h (steps 4-6)      then attnb/E (steps 9-11)
    //   R1 (32MB): embb (steps 1-4)   then featT (steps 8-11)
    //   R2 (32MB): feat (steps 6-9)   then attd (steps 11-12)
    char* R0 = ws + alloc((size_t)M * H1 * 2);
    char* R1 = ws + alloc((size_t)M * DIN * 2);
    char* R2 = ws + alloc((size_t)M * H2 * 2);
    u16* W1t = (u16*)(ws + alloc((size_t)H1 * DIN * 2));
    u16* W2t = (u16*)(ws + alloc((size_t)H2 * H1 * 2));
    u16* WhT = (u16*)(ws + alloc((size_t)Cc * H2 * 2));
    float* rowInv = (float*)(ws + alloc((size_t)M * 4));

    u16* h = (u16*)R0;
    u16* attnb = (u16*)R0;
    u16* embb = (u16*)R1;
    u16* featT = (u16*)R1;
    u16* feat = (u16*)R2;
    u16* attd = (u16*)R2;

    float* out_logits = (float*)d_out;
    float* out_attn = out_logits + (size_t)M * Cc;

    // 1. embeddings -> bf16
    cvt_kernel<<<(int)(((long)M * DIN) / 1024), 256, 0, stream>>>(emb, embb, (long)M * DIN);
    // 2. W1 [DIN][H1] -> W1t [H1][DIN]
    transpose_to_bf16<1><<<dim3(H1 / 32, DIN / 32, 1), 256, 0, stream>>>(W1, W1t, DIN, H1, 0, 0);
    // 3. W2 [H1][H2] -> W2t [H2][H1]
    transpose_to_bf16<1><<<dim3(H2 / 32, H1 / 32, 1), 256, 0, stream>>>(W2, W2t, H1, H2, 0, 0);
    // 3b. Wh [H2][C] -> WhT [C][H2]
    transpose_to_bf16<1><<<dim3(Cc / 32, H2 / 32, 1), 256, 0, stream>>>(Wh, WhT, H2, Cc, 0, 0);
    // 4. h = relu(emb @ W1 + b1)   [M,H1] bf16
    gemm_nt<1><<<dim3(H1 / 256, M / 256, 1), 512, 0, stream>>>(embb, W1t, h, M, H1, DIN, 0, 0, 0,
                                                               b1, 1, 1.0f, 0, nullptr);
    // 5. LN1 (wave-per-row)
    ln_wave<4><<<M / 4, 256, 0, stream>>>(h, g1, be1);
    // 6. feat = relu(h @ W2 + b2)  [M,H2] bf16
    gemm_nt<1><<<dim3(H2 / 256, M / 256, 1), 512, 0, stream>>>(h, W2t, feat, M, H2, H1, 0, 0, 0,
                                                               b2, 1, 1.0f, 0, nullptr);
    // 7. LN2
    ln_wave<2><<<M / 4, 256, 0, stream>>>(feat, g2, be2);
    // 8. featT per batch: [S][H2] -> [H2][S]
    transpose_to_bf16<0><<<dim3(H2 / 32, S / 32, Bn), 256, 0, stream>>>(
        feat, featT, S, H2, (long)S * H2, (long)H2 * S);
    // 9. E = exp(feat@feat^T/32 - 32) bf16 -> attnb, balanced triangle + LDS mirror
    {
        const int NB = S / 256;              // 8
        const int nTri = NB * (NB + 1) / 2;  // 36
        gemm_nt<1><<<dim3(nTri * Bn, 1, 1), 512, 0, stream>>>(
            feat, feat, attnb, S, S, H2, (long)S * H2, (long)S * H2, (long)S * S, nullptr,
            /*act=*/2, 0.03125f, /*symm=*/1, nullptr);
    }
    // 10. normalize: attention weights fp32 -> d_out, rowInv for attended
    norm_wave<<<M / 4, 256, 0, stream>>>(attnb, out_attn, rowInv);
    // 11. attended = (E @ featT) * rowInv   [S,H2] bf16 per batch
    gemm_nt<1><<<dim3(H2 / 256, S / 256, Bn), 512, 0, stream>>>(attnb, featT, attd, S, H2, S,
                                                                (long)S * S, (long)H2 * S,
                                                                (long)S * H2, nullptr, 0, 1.0f, 0,
                                                                rowInv);
    // 12. head + logic gates + log (MFMA)
    head_kernel<<<M / 128, 256, 0, stream>>>(attd, WhT, bh, prior, ag, og, out_logits);
}